// Round 1
// baseline (558.807 us; speedup 1.0000x reference)
//
#include <hip/hip_runtime.h>
#include <hip/hip_bf16.h>
#include <math.h>

// Problem constants
#define N_ROWS 16384
#define N_A    256
#define N_F    2048
#define GAMMA  1.5f
#define BN_EPS 1e-5f

typedef __attribute__((ext_vector_type(8))) short short8;
typedef __attribute__((ext_vector_type(4))) float f32x4;

// ---------------------------------------------------------------------------
// K0: fp32 -> bf16 conversion (4 elements/thread, vectorized)
// ---------------------------------------------------------------------------
__global__ __launch_bounds__(256) void cvt_bf16(const float* __restrict__ in,
                                                unsigned short* __restrict__ out,
                                                int n4) {
    int i = blockIdx.x * 256 + threadIdx.x;
    if (i >= n4) return;
    float4 v = reinterpret_cast<const float4*>(in)[i];
    ushort4 o;
    __hip_bfloat16 hx = __float2bfloat16(v.x);
    __hip_bfloat16 hy = __float2bfloat16(v.y);
    __hip_bfloat16 hz = __float2bfloat16(v.z);
    __hip_bfloat16 hw = __float2bfloat16(v.w);
    o.x = __builtin_bit_cast(unsigned short, hx);
    o.y = __builtin_bit_cast(unsigned short, hy);
    o.z = __builtin_bit_cast(unsigned short, hz);
    o.w = __builtin_bit_cast(unsigned short, hw);
    reinterpret_cast<ushort4*>(out)[i] = o;
}

// ---------------------------------------------------------------------------
// K1: x = a @ W^T + b  (bf16 MFMA, fp32 accumulate)
// a: [N][256] bf16 (ws), W: [F][256] bf16 (ws), x: [N][F] fp32 (d_out m-region)
// Block = 256 threads = 4 waves; wave computes 16(M) x 64(F); block 64x64.
// Both operands are K-contiguous (B^T GEMM): each lane loads 8 contiguous
// bf16 = 16 B per fragment.
// A-frag: A[m=lane&15][k = quad*8 + j]; B-frag: W[f=lane&15][k = quad*8 + j]
// C/D:    row = quad*4 + r, col = lane&15   [m89-verified layout]
// ---------------------------------------------------------------------------
__global__ __launch_bounds__(256) void gemm_x(const unsigned short* __restrict__ aB,
                                              const unsigned short* __restrict__ wB,
                                              const float* __restrict__ bias,
                                              float* __restrict__ x) {
    const int lane = threadIdx.x & 63;
    const int wave = threadIdx.x >> 6;
    const int r16  = lane & 15;
    const int quad = lane >> 4;
    const int row0 = blockIdx.y * 64 + wave * 16;  // M
    const int col0 = blockIdx.x * 64;              // F

    f32x4 acc[4] = {{0.f,0.f,0.f,0.f},{0.f,0.f,0.f,0.f},
                    {0.f,0.f,0.f,0.f},{0.f,0.f,0.f,0.f}};

    const unsigned short* aRow = aB + (size_t)(row0 + r16) * N_A;
    const unsigned short* wRow0 = wB + (size_t)(col0 + r16) * N_A;

    #pragma unroll
    for (int ks = 0; ks < 8; ++ks) {
        const int k0 = ks * 32 + quad * 8;
        short8 afrag = *reinterpret_cast<const short8*>(aRow + k0);
        #pragma unroll
        for (int t = 0; t < 4; ++t) {
            short8 bfrag = *reinterpret_cast<const short8*>(wRow0 + (size_t)t * 16 * N_A + k0);
            acc[t] = __builtin_amdgcn_mfma_f32_16x16x32_bf16(afrag, bfrag, acc[t], 0, 0, 0);
        }
    }

    #pragma unroll
    for (int t = 0; t < 4; ++t) {
        const int col = col0 + t * 16 + r16;
        const float bcol = bias[col];
        #pragma unroll
        for (int r = 0; r < 4; ++r) {
            const int row = row0 + quad * 4 + r;
            x[(size_t)row * N_F + col] = acc[t][r] + bcol;
        }
    }
}

// ---------------------------------------------------------------------------
// K2: per-feature partial sums (deterministic two-stage, no atomics)
// grid (8, 64): blockIdx.x covers features in chunks of 256, blockIdx.y covers
// rows in chunks of 256. Coalesced: consecutive threads = consecutive f.
// ---------------------------------------------------------------------------
__global__ __launch_bounds__(256) void colstats_partial(const float* __restrict__ x,
                                                        float* __restrict__ ps1,
                                                        float* __restrict__ ps2) {
    const int f  = blockIdx.x * 256 + threadIdx.x;
    const int rc = blockIdx.y;
    const float* p = x + (size_t)rc * 256 * N_F + f;
    float s1 = 0.f, s2 = 0.f;
    #pragma unroll 4
    for (int n = 0; n < 256; ++n) {
        float v = p[(size_t)n * N_F];
        s1 += v;
        s2 += v * v;
    }
    ps1[rc * N_F + f] = s1;
    ps2[rc * N_F + f] = s2;
}

// ---------------------------------------------------------------------------
// K3: finalize BN stats -> per-feature scale/shift
// ---------------------------------------------------------------------------
__global__ __launch_bounds__(256) void finalize_stats(const float* __restrict__ ps1,
                                                      const float* __restrict__ ps2,
                                                      const float* __restrict__ bn_w,
                                                      const float* __restrict__ bn_b,
                                                      float* __restrict__ scale,
                                                      float* __restrict__ shift) {
    const int f = blockIdx.x * 256 + threadIdx.x;
    float s1 = 0.f, s2 = 0.f;
    for (int i = 0; i < 64; ++i) {
        s1 += ps1[i * N_F + f];
        s2 += ps2[i * N_F + f];
    }
    const float inv_n = 1.0f / (float)N_ROWS;
    const float mu  = s1 * inv_n;
    const float var = s2 * inv_n - mu * mu;
    const float sc  = bn_w[f] / sqrtf(var + BN_EPS);
    scale[f] = sc;
    shift[f] = bn_b[f] - mu * sc;
}

// ---------------------------------------------------------------------------
// K4: fused BN + sparsemax + prior update. One block (256 thr) per row.
// Sparsemax shortcut (see analysis): the reference's ascending-sort predicate
// is monotone, so k_z = D-1 iff 1 + (D-1)*max(z) - sum(z) > 0 (always here),
// giving tau = (sum(z)+1)/(D-1). Degenerate fallback replicated exactly.
// z kept in registers; x region (== m region) overwritten after reads.
// ---------------------------------------------------------------------------
__global__ __launch_bounds__(256) void bn_sparsemax(const float* __restrict__ x,
                                                    const float* __restrict__ ps,
                                                    const float* __restrict__ scale,
                                                    const float* __restrict__ shift,
                                                    float* __restrict__ m_out,
                                                    float* __restrict__ ps_out) {
    const int row = blockIdx.x;
    const int tid = threadIdx.x;
    const float* xr = x  + (size_t)row * N_F;
    const float* pr = ps + (size_t)row * N_F;

    float z[8], p[8];
    float s = 0.f, mx = -INFINITY, mn = INFINITY;

    #pragma unroll
    for (int c = 0; c < 2; ++c) {
        const int f = c * 1024 + tid * 4;
        float4 xv = *reinterpret_cast<const float4*>(xr + f);
        float4 pv = *reinterpret_cast<const float4*>(pr + f);
        float4 sc = *reinterpret_cast<const float4*>(scale + f);
        float4 sh = *reinterpret_cast<const float4*>(shift + f);
        float zz;
        zz = (xv.x * sc.x + sh.x) * pv.x; z[c*4+0] = zz; p[c*4+0] = pv.x; s += zz; mx = fmaxf(mx, zz); mn = fminf(mn, zz);
        zz = (xv.y * sc.y + sh.y) * pv.y; z[c*4+1] = zz; p[c*4+1] = pv.y; s += zz; mx = fmaxf(mx, zz); mn = fminf(mn, zz);
        zz = (xv.z * sc.z + sh.z) * pv.z; z[c*4+2] = zz; p[c*4+2] = pv.z; s += zz; mx = fmaxf(mx, zz); mn = fminf(mn, zz);
        zz = (xv.w * sc.w + sh.w) * pv.w; z[c*4+3] = zz; p[c*4+3] = pv.w; s += zz; mx = fmaxf(mx, zz); mn = fminf(mn, zz);
    }

    // wave (64-lane) butterfly reduction
    #pragma unroll
    for (int off = 32; off > 0; off >>= 1) {
        s  += __shfl_xor(s, off);
        mx  = fmaxf(mx, __shfl_xor(mx, off));
        mn  = fminf(mn, __shfl_xor(mn, off));
    }
    __shared__ float rs[4], rmx[4], rmn[4];
    const int wave = tid >> 6;
    if ((tid & 63) == 0) { rs[wave] = s; rmx[wave] = mx; rmn[wave] = mn; }
    __syncthreads();
    s  = rs[0] + rs[1] + rs[2] + rs[3];
    mx = fmaxf(fmaxf(rmx[0], rmx[1]), fmaxf(rmx[2], rmx[3]));
    mn = fminf(fminf(rmn[0], rmn[1]), fminf(rmn[2], rmn[3]));

    const float c_last = 1.0f + (float)(N_F - 1) * mx - s;
    float tau;
    if (c_last > 0.0f) {
        tau = (s + 1.0f) / (float)(N_F - 1);
    } else {
        // reference degenerate branch: k_z = 0, m_z = min; tau = (min+1)/0.0
        tau = (mn + 1.0f) / 0.0f;
    }

    float* mo = m_out  + (size_t)row * N_F;
    float* po = ps_out + (size_t)row * N_F;
    #pragma unroll
    for (int c = 0; c < 2; ++c) {
        const int f = c * 1024 + tid * 4;
        float4 mv, pv;
        mv.x = fmaxf(z[c*4+0] - tau, 0.f); pv.x = p[c*4+0] * (GAMMA - mv.x);
        mv.y = fmaxf(z[c*4+1] - tau, 0.f); pv.y = p[c*4+1] * (GAMMA - mv.y);
        mv.z = fmaxf(z[c*4+2] - tau, 0.f); pv.z = p[c*4+2] * (GAMMA - mv.z);
        mv.w = fmaxf(z[c*4+3] - tau, 0.f); pv.w = p[c*4+3] * (GAMMA - mv.w);
        *reinterpret_cast<float4*>(mo + f) = mv;
        *reinterpret_cast<float4*>(po + f) = pv;
    }
}

// ---------------------------------------------------------------------------
extern "C" void kernel_launch(void* const* d_in, const int* in_sizes, int n_in,
                              void* d_out, int out_size, void* d_ws, size_t ws_size,
                              hipStream_t stream) {
    const float* a    = (const float*)d_in[0];  // [N, 256]
    const float* ps   = (const float*)d_in[1];  // [N, 2048]
    const float* W    = (const float*)d_in[2];  // [2048, 256]
    const float* bias = (const float*)d_in[3];  // [2048]
    const float* bnw  = (const float*)d_in[4];
    const float* bnb  = (const float*)d_in[5];

    float* out    = (float*)d_out;
    float* x      = out;                               // stash x in m-region
    float* m_out  = out;
    float* ps_out = out + (size_t)N_ROWS * N_F;

    // ws layout
    char* ws = (char*)d_ws;
    unsigned short* aB = (unsigned short*)ws;                           // 8 MB
    unsigned short* wB = (unsigned short*)(ws + 8388608);               // 1 MB
    float* ps1   = (float*)(ws + 9437184);                              // 512 KB
    float* ps2   = (float*)(ws + 9961472);                              // 512 KB
    float* scale = (float*)(ws + 10485760);                             // 8 KB
    float* shift = (float*)(ws + 10493952);                             // 8 KB

    cvt_bf16<<<(N_ROWS * N_A / 4 + 255) / 256, 256, 0, stream>>>(a, aB, N_ROWS * N_A / 4);
    cvt_bf16<<<(N_F * N_A / 4 + 255) / 256, 256, 0, stream>>>(W, wB, N_F * N_A / 4);
    gemm_x<<<dim3(N_F / 64, N_ROWS / 64), 256, 0, stream>>>(aB, wB, bias, x);
    colstats_partial<<<dim3(N_F / 256, 64), 256, 0, stream>>>(x, ps1, ps2);
    finalize_stats<<<N_F / 256, 256, 0, stream>>>(ps1, ps2, bnw, bnb, scale, shift);
    bn_sparsemax<<<N_ROWS, 256, 0, stream>>>(x, ps, scale, shift, m_out, ps_out);
}

// Round 2
// 492.269 us; speedup vs baseline: 1.1352x; 1.1352x over previous
//
#include <hip/hip_runtime.h>
#include <hip/hip_bf16.h>
#include <math.h>

// Problem constants
#define N_ROWS 16384
#define N_A    256
#define N_F    2048
#define GAMMA  1.5f
#define BN_EPS 1e-5f

typedef __attribute__((ext_vector_type(8))) short short8;
typedef __attribute__((ext_vector_type(4))) float f32x4;

// ---------------------------------------------------------------------------
// K0: fp32 -> bf16 conversion (4 elements/thread, vectorized)
// ---------------------------------------------------------------------------
__global__ __launch_bounds__(256) void cvt_bf16(const float* __restrict__ in,
                                                unsigned short* __restrict__ out,
                                                int n4) {
    int i = blockIdx.x * 256 + threadIdx.x;
    if (i >= n4) return;
    float4 v = reinterpret_cast<const float4*>(in)[i];
    ushort4 o;
    o.x = __builtin_bit_cast(unsigned short, __float2bfloat16(v.x));
    o.y = __builtin_bit_cast(unsigned short, __float2bfloat16(v.y));
    o.z = __builtin_bit_cast(unsigned short, __float2bfloat16(v.z));
    o.w = __builtin_bit_cast(unsigned short, __float2bfloat16(v.w));
    reinterpret_cast<ushort4*>(out)[i] = o;
}

// ---------------------------------------------------------------------------
// K1: x = a @ W^T + b  (bf16 MFMA, fp32 acc), 128x128 block tile.
// Fused: (a) per-column partial sums s1/s2 for BatchNorm (shfl + LDS reduce,
// deterministic partials indexed by blockIdx.y), (b) x stored as bf16 via LDS
// transpose -> fully coalesced 64 MB instead of scattered 128 MB fp32.
// xB row stride = 4096 ushorts (bf16 x lives in the first half of each
// 8 KB m-row of d_out; bn_sparsemax reads it before overwriting).
// Wave w: rows [w*32, w*32+32), all 128 cols. acc[g][t]: rowgroup g (16 rows),
// coltile t (16 cols). Fragment layouts per m89/m91 verification.
// ---------------------------------------------------------------------------
__global__ __launch_bounds__(256) void gemm_x(const unsigned short* __restrict__ aB,
                                              const unsigned short* __restrict__ wB,
                                              const float* __restrict__ bias,
                                              unsigned short* __restrict__ xB,
                                              float* __restrict__ ps1,
                                              float* __restrict__ ps2) {
    const int lane = threadIdx.x & 63;
    const int wave = threadIdx.x >> 6;
    const int r16  = lane & 15;
    const int quad = lane >> 4;
    const int col0 = blockIdx.x * 128;
    const int rowB = blockIdx.y * 128;
    const int row0 = rowB + wave * 32;

    f32x4 acc[2][8];
    #pragma unroll
    for (int g = 0; g < 2; ++g)
        #pragma unroll
        for (int t = 0; t < 8; ++t)
            acc[g][t] = (f32x4){0.f, 0.f, 0.f, 0.f};

    const unsigned short* aR0 = aB + (size_t)(row0 + r16) * N_A;
    const unsigned short* aR1 = aR0 + 16 * N_A;
    const unsigned short* wR  = wB + (size_t)(col0 + r16) * N_A;

    #pragma unroll
    for (int ks = 0; ks < 8; ++ks) {
        const int k0 = ks * 32 + quad * 8;
        short8 a0 = *reinterpret_cast<const short8*>(aR0 + k0);
        short8 a1 = *reinterpret_cast<const short8*>(aR1 + k0);
        #pragma unroll
        for (int t = 0; t < 8; ++t) {
            short8 bf = *reinterpret_cast<const short8*>(wR + (size_t)t * 16 * N_A + k0);
            acc[0][t] = __builtin_amdgcn_mfma_f32_16x16x32_bf16(a0, bf, acc[0][t], 0, 0, 0);
            acc[1][t] = __builtin_amdgcn_mfma_f32_16x16x32_bf16(a1, bf, acc[1][t], 0, 0, 0);
        }
    }

    __shared__ float cs1[4][128];
    __shared__ float cs2[4][128];
    __shared__ unsigned short tile[128][136];   // +8 pad vs 128 to break bank stride

    #pragma unroll
    for (int t = 0; t < 8; ++t) {
        const float bcol = bias[col0 + t * 16 + r16];
        float s1 = 0.f, s2 = 0.f;
        #pragma unroll
        for (int g = 0; g < 2; ++g) {
            #pragma unroll
            for (int r = 0; r < 4; ++r) {
                float v = acc[g][t][r] + bcol;
                s1 += v;
                s2 += v * v;
                tile[wave * 32 + g * 16 + quad * 4 + r][t * 16 + r16] =
                    __builtin_bit_cast(unsigned short, __float2bfloat16(v));
            }
        }
        // reduce across the 4 quads (rows) -> per-column sums over 32 rows
        s1 += __shfl_xor(s1, 16); s1 += __shfl_xor(s1, 32);
        s2 += __shfl_xor(s2, 16); s2 += __shfl_xor(s2, 32);
        if (quad == 0) { cs1[wave][t * 16 + r16] = s1; cs2[wave][t * 16 + r16] = s2; }
    }
    __syncthreads();

    if (threadIdx.x < 128) {
        const int c = threadIdx.x;
        float s1 = cs1[0][c] + cs1[1][c] + cs1[2][c] + cs1[3][c];
        float s2 = cs2[0][c] + cs2[1][c] + cs2[2][c] + cs2[3][c];
        ps1[(size_t)blockIdx.y * N_F + col0 + c] = s1;
        ps2[(size_t)blockIdx.y * N_F + col0 + c] = s2;
    }

    // coalesced bf16 tile store: 256 threads x 128 B each
    {
        const int r = threadIdx.x >> 1;
        const int h = threadIdx.x & 1;
        const unsigned short* src = &tile[r][h * 64];
        unsigned short* dst = xB + (size_t)(rowB + r) * 4096 + col0 + h * 64;
        #pragma unroll
        for (int i = 0; i < 8; ++i)
            *reinterpret_cast<short8*>(dst + i * 8) =
                *reinterpret_cast<const short8*>(src + i * 8);
    }
}

// ---------------------------------------------------------------------------
// K2: finalize BN stats (sum 128 deterministic partials) -> scale/shift
// ---------------------------------------------------------------------------
__global__ __launch_bounds__(256) void finalize_stats(const float* __restrict__ ps1,
                                                      const float* __restrict__ ps2,
                                                      const float* __restrict__ bn_w,
                                                      const float* __restrict__ bn_b,
                                                      float* __restrict__ scale,
                                                      float* __restrict__ shift) {
    const int f = blockIdx.x * 256 + threadIdx.x;
    float s1 = 0.f, s2 = 0.f;
    #pragma unroll 4
    for (int i = 0; i < 128; ++i) {
        s1 += ps1[(size_t)i * N_F + f];
        s2 += ps2[(size_t)i * N_F + f];
    }
    const float inv_n = 1.0f / (float)N_ROWS;
    const float mu  = s1 * inv_n;
    const float var = s2 * inv_n - mu * mu;
    const float sc  = bn_w[f] / sqrtf(var + BN_EPS);
    scale[f] = sc;
    shift[f] = bn_b[f] - mu * sc;
}

// ---------------------------------------------------------------------------
// K3: fused BN + sparsemax + prior update. One block (256 thr) per row.
// Sparsemax shortcut (validated round 1, absmax 0.031): reference's
// ascending-sort predicate is monotone -> tau = (sum+1)/(D-1) when
// 1+(D-1)*max-sum > 0, else the exact degenerate fallback.
// Reads bf16 x from the first 4096 B of its own m-row (written by gemm_x);
// the block's __syncthreads orders all reads before the overwriting stores.
// NOTE: xB and m_out alias — no __restrict__ on them.
// ---------------------------------------------------------------------------
__global__ __launch_bounds__(256) void bn_sparsemax(const unsigned short* xB,
                                                    const float* __restrict__ ps,
                                                    const float* __restrict__ scale,
                                                    const float* __restrict__ shift,
                                                    float* m_out,
                                                    float* __restrict__ ps_out) {
    const int row = blockIdx.x;
    const int tid = threadIdx.x;
    const int f0  = tid * 8;

    const unsigned short* xr = xB + (size_t)row * 4096 + f0;
    const float* pr = ps + (size_t)row * N_F + f0;

    short8 xv = *reinterpret_cast<const short8*>(xr);
    float4 p0  = *reinterpret_cast<const float4*>(pr);
    float4 p1  = *reinterpret_cast<const float4*>(pr + 4);
    float4 sc0 = *reinterpret_cast<const float4*>(scale + f0);
    float4 sc1 = *reinterpret_cast<const float4*>(scale + f0 + 4);
    float4 sh0 = *reinterpret_cast<const float4*>(shift + f0);
    float4 sh1 = *reinterpret_cast<const float4*>(shift + f0 + 4);

    float pv[8]  = {p0.x, p0.y, p0.z, p0.w, p1.x, p1.y, p1.z, p1.w};
    float scv[8] = {sc0.x, sc0.y, sc0.z, sc0.w, sc1.x, sc1.y, sc1.z, sc1.w};
    float shv[8] = {sh0.x, sh0.y, sh0.z, sh0.w, sh1.x, sh1.y, sh1.z, sh1.w};

    float z[8];
    float s = 0.f, mx = -INFINITY, mn = INFINITY;
    #pragma unroll
    for (int i = 0; i < 8; ++i) {
        float xf = __builtin_bit_cast(float,
                       (unsigned int)((unsigned short)xv[i]) << 16);
        float zz = (xf * scv[i] + shv[i]) * pv[i];
        z[i] = zz;
        s += zz;
        mx = fmaxf(mx, zz);
        mn = fminf(mn, zz);
    }

    // wave (64-lane) butterfly reduction
    #pragma unroll
    for (int off = 32; off > 0; off >>= 1) {
        s  += __shfl_xor(s, off);
        mx  = fmaxf(mx, __shfl_xor(mx, off));
        mn  = fminf(mn, __shfl_xor(mn, off));
    }
    __shared__ float rs[4], rmx[4], rmn[4];
    const int wave = tid >> 6;
    if ((tid & 63) == 0) { rs[wave] = s; rmx[wave] = mx; rmn[wave] = mn; }
    __syncthreads();   // also orders xB reads before the aliased m_out writes
    s  = rs[0] + rs[1] + rs[2] + rs[3];
    mx = fmaxf(fmaxf(rmx[0], rmx[1]), fmaxf(rmx[2], rmx[3]));
    mn = fminf(fminf(rmn[0], rmn[1]), fminf(rmn[2], rmn[3]));

    const float c_last = 1.0f + (float)(N_F - 1) * mx - s;
    float tau;
    if (c_last > 0.0f) {
        tau = (s + 1.0f) / (float)(N_F - 1);
    } else {
        tau = (mn + 1.0f) / 0.0f;   // reference degenerate branch (k_z = 0)
    }

    float* mo = m_out  + (size_t)row * N_F + f0;
    float* po = ps_out + (size_t)row * N_F + f0;
    float4 mv0, mv1, po0, po1;
    mv0.x = fmaxf(z[0] - tau, 0.f); po0.x = pv[0] * (GAMMA - mv0.x);
    mv0.y = fmaxf(z[1] - tau, 0.f); po0.y = pv[1] * (GAMMA - mv0.y);
    mv0.z = fmaxf(z[2] - tau, 0.f); po0.z = pv[2] * (GAMMA - mv0.z);
    mv0.w = fmaxf(z[3] - tau, 0.f); po0.w = pv[3] * (GAMMA - mv0.w);
    mv1.x = fmaxf(z[4] - tau, 0.f); po1.x = pv[4] * (GAMMA - mv1.x);
    mv1.y = fmaxf(z[5] - tau, 0.f); po1.y = pv[5] * (GAMMA - mv1.y);
    mv1.z = fmaxf(z[6] - tau, 0.f); po1.z = pv[6] * (GAMMA - mv1.z);
    mv1.w = fmaxf(z[7] - tau, 0.f); po1.w = pv[7] * (GAMMA - mv1.w);
    *reinterpret_cast<float4*>(mo)     = mv0;
    *reinterpret_cast<float4*>(mo + 4) = mv1;
    *reinterpret_cast<float4*>(po)     = po0;
    *reinterpret_cast<float4*>(po + 4) = po1;
}

// ---------------------------------------------------------------------------
extern "C" void kernel_launch(void* const* d_in, const int* in_sizes, int n_in,
                              void* d_out, int out_size, void* d_ws, size_t ws_size,
                              hipStream_t stream) {
    const float* a    = (const float*)d_in[0];  // [N, 256]
    const float* ps   = (const float*)d_in[1];  // [N, 2048]
    const float* W    = (const float*)d_in[2];  // [2048, 256]
    const float* bias = (const float*)d_in[3];  // [2048]
    const float* bnw  = (const float*)d_in[4];
    const float* bnb  = (const float*)d_in[5];

    float* out    = (float*)d_out;
    float* m_out  = out;
    float* ps_out = out + (size_t)N_ROWS * N_F;
    // bf16 x lives interleaved in the m region: row r occupies the first
    // 4096 B of m-row r (stride 4096 ushorts = 8192 B).
    unsigned short* xB = (unsigned short*)d_out;

    char* ws = (char*)d_ws;
    unsigned short* aB = (unsigned short*)ws;                    // 8 MB
    unsigned short* wB = (unsigned short*)(ws + (8u << 20));     // 1 MB
    float* ps1   = (float*)(ws + (9u  << 20));                   // 1 MB (128x2048)
    float* ps2   = (float*)(ws + (10u << 20));                   // 1 MB
    float* scale = (float*)(ws + (11u << 20));                   // 8 KB
    float* shift = (float*)(ws + (11u << 20) + 8192);            // 8 KB

    cvt_bf16<<<4096, 256, 0, stream>>>(a, aB, N_ROWS * N_A / 4);
    cvt_bf16<<<512, 256, 0, stream>>>(W, wB, N_F * N_A / 4);
    gemm_x<<<dim3(N_F / 128, N_ROWS / 128), 256, 0, stream>>>(aB, wB, bias, xB, ps1, ps2);
    finalize_stats<<<N_F / 256, 256, 0, stream>>>(ps1, ps2, bnw, bnb, scale, shift);
    bn_sparsemax<<<N_ROWS, 256, 0, stream>>>(xB, ps, scale, shift, m_out, ps_out);
}